// Round 6
// baseline (129.273 us; speedup 1.0000x reference)
//
#include <hip/hip_runtime.h>

#define Bb 4
#define Nn 1024
#define Dd 128
#define Hh 64

typedef float v2f __attribute__((ext_vector_type(2)));
typedef float v4f __attribute__((ext_vector_type(4)));

__device__ __forceinline__ v2f pk_add(v2f a, v2f b) {
    v2f d;
    asm("v_pk_add_f32 %0, %1, %2" : "=v"(d) : "v"(a), "v"(b));
    return d;
}
__device__ __forceinline__ void pk_fma(v2f& d, v2f a, v2f b) {
    asm("v_pk_fma_f32 %0, %1, %2, %0" : "+v"(d) : "v"(a), "v"(b));
}

__device__ __forceinline__ float fast_tanh(float x) {
    const float e = __expf(2.0f * x);
    return __fdividef(e - 1.0f, e + 1.0f);
}

// word-index swizzle inside a [rows][64] f32 panel (XOR row bits into 16B-slot bits)
__device__ __forceinline__ int swz(int row, int cw) {
    return row * Hh + (cw ^ (((row >> 2) & 7) << 2));
}

// ---------------- Kernel A: projection ----------------
__global__ __launch_bounds__(512) void proj_kernel(
    const float* __restrict__ emb, const float* __restrict__ W1,
    const float* __restrict__ b1, float* __restrict__ HI2, float* __restrict__ HJ)
{
    __shared__ float se[16][132];
    const int tid = threadIdx.x;
    const int row0 = blockIdx.x * 16;
    {
        const int r = tid >> 5;
        const int c = tid & 31;
        const float4 v = *(const float4*)(emb + (size_t)(row0 + r) * Dd + c * 4);
        *(float4*)&se[r][c * 4] = v;
    }
    __syncthreads();
    const int r  = tid >> 5;
    const int h2 = (tid & 31) * 2;
    float2 acc1 = *(const float2*)(b1 + h2);
    float2 acc2 = make_float2(0.f, 0.f);
    const float* er = se[r];
    #pragma unroll 8
    for (int d = 0; d < Dd; ++d) {
        const float ev = er[d];
        const float2 wa = *(const float2*)(W1 + (size_t)d * Hh + h2);
        const float2 wb = *(const float2*)(W1 + (size_t)(d + Dd) * Hh + h2);
        acc1.x = fmaf(ev, wa.x, acc1.x); acc1.y = fmaf(ev, wa.y, acc1.y);
        acc2.x = fmaf(ev, wb.x, acc2.x); acc2.y = fmaf(ev, wb.y, acc2.y);
    }
    *(float2*)(HI2 + (size_t)(row0 + r) * Hh + h2) = acc1;
    *(float2*)(HJ  + (size_t)(row0 + r) * Hh + h2) = acc2;
}

// ---------------- Kernel B: one-directional raw scores ----------------
// 128x64 tile, 256 thr (16x16), 8x4 micro, packed-f32 math.
// S[b,i,j] = sum_h relu(HI2[i,h]+HJ[j,h]) * W2[h]
__global__ __launch_bounds__(256) void score_kernel(
    const float* __restrict__ HI2, const float* __restrict__ HJ,
    const float* __restrict__ W2, float* __restrict__ S)
{
    __shared__ float sA[128 * Hh];  // 32 KB, i-rows (HI2), swizzled
    __shared__ float sB[64 * Hh];   // 16 KB, j-rows (HJ),  swizzled

    const int tid = threadIdx.x;
    const int blk = blockIdx.x;
    const int b   = blk >> 7;       // 128 tiles per batch
    const int rem = blk & 127;
    const int ti  = rem >> 4;       // 0..7  (128-row i tiles)
    const int tj  = rem & 15;       // 0..15 (64-col j tiles)
    const int ri0 = ti * 128, rj0 = tj * 64;

    const float* HIb = HI2 + ((size_t)b * Nn + ri0) * Hh;
    const float* HJb = HJ  + ((size_t)b * Nn + rj0) * Hh;

    // stage: sA 2048 float4 (k=0..7), sB 1024 float4 (k=8..11)
    #pragma unroll
    for (int k = 0; k < 12; ++k) {
        const int l = tid + k * 256;
        if (k < 8) {
            const int row = l >> 4;
            const int cw  = (l & 15) * 4;
            const float4 v = *(const float4*)(HIb + row * Hh + cw);
            *(float4*)&sA[swz(row, cw)] = v;
        } else {
            const int m   = l - 2048;
            const int row = m >> 4;
            const int cw  = (m & 15) * 4;
            const float4 v = *(const float4*)(HJb + row * Hh + cw);
            *(float4*)&sB[swz(row, cw)] = v;
        }
    }
    __syncthreads();

    const int ty = tid >> 4;        // i direction, 8 rows each
    const int tx = tid & 15;        // j direction, 4 cols each
    const int ar0 = ty * 8, br0 = tx * 4;

    int abase[8], axor[8];
    #pragma unroll
    for (int r = 0; r < 8; ++r) {
        abase[r] = (ar0 + r) * Hh;
        axor[r]  = (((ar0 + r) >> 2) & 7) << 2;
    }
    int bbase[4], bxor[4];
    #pragma unroll
    for (int c = 0; c < 4; ++c) {
        bbase[c] = (br0 + c) * Hh;
        bxor[c]  = (((br0 + c) >> 2) & 7) << 2;
    }

    v2f acc[8][4];
    #pragma unroll
    for (int r = 0; r < 8; ++r)
        #pragma unroll
        for (int c = 0; c < 4; ++c) acc[r][c] = (v2f){0.f, 0.f};

    #pragma unroll 4
    for (int hc = 0; hc < 16; ++hc) {
        const int cw = hc * 4;
        const float4 wv = *(const float4*)(W2 + cw);   // uniform -> s_load
        const v2f w01 = {wv.x, wv.y};
        const v2f w23 = {wv.z, wv.w};

        v2f blo[4], bhi[4];
        #pragma unroll
        for (int c = 0; c < 4; ++c) {
            const v4f bv = *(const v4f*)&sB[bbase[c] + (cw ^ bxor[c])];
            blo[c] = __builtin_shufflevector(bv, bv, 0, 1);
            bhi[c] = __builtin_shufflevector(bv, bv, 2, 3);
        }
        #pragma unroll
        for (int r = 0; r < 8; ++r) {
            const v4f av = *(const v4f*)&sA[abase[r] + (cw ^ axor[r])];
            const v2f alo = __builtin_shufflevector(av, av, 0, 1);
            const v2f ahi = __builtin_shufflevector(av, av, 2, 3);
            #pragma unroll
            for (int c = 0; c < 4; ++c) {
                v2f x0 = pk_add(alo, blo[c]);
                v2f x1 = pk_add(ahi, bhi[c]);
                x0.x = fmaxf(x0.x, 0.f); x0.y = fmaxf(x0.y, 0.f);
                x1.x = fmaxf(x1.x, 0.f); x1.y = fmaxf(x1.y, 0.f);
                pk_fma(acc[r][c], x0, w01);
                pk_fma(acc[r][c], x1, w23);
            }
        }
    }

    float* Sb = S + (size_t)b * Nn * Nn;
    const int i0 = ri0 + ar0;
    const int j0 = rj0 + br0;
    #pragma unroll
    for (int r = 0; r < 8; ++r) {
        float4 v;
        v.x = acc[r][0].x + acc[r][0].y;
        v.y = acc[r][1].x + acc[r][1].y;
        v.z = acc[r][2].x + acc[r][2].y;
        v.w = acc[r][3].x + acc[r][3].y;
        *(float4*)(Sb + (size_t)(i0 + r) * Nn + j0) = v;
    }
}

// ---------------- Kernel C: symmetrize + tanh ----------------
__global__ __launch_bounds__(256) void sym_kernel(
    const float* __restrict__ S, const float* __restrict__ b2p,
    float* __restrict__ out)
{
    __shared__ float bT[64][68];
    const int tid = threadIdx.x;
    const int blk = blockIdx.x;
    const int b  = blk >> 8;
    const int p  = blk & 255;
    const int ti = p >> 4;
    const int tj = p & 15;
    const int i0 = ti * 64, j0 = tj * 64;
    const float* Sb = S + (size_t)b * Nn * Nn;

    #pragma unroll
    for (int k = 0; k < 4; ++k) {
        const int l = tid + k * 256;
        const int jj = l >> 4;
        const int c4 = (l & 15) * 4;
        const float4 v = *(const float4*)(Sb + (size_t)(j0 + jj) * Nn + i0 + c4);
        *(float4*)&bT[jj][c4] = v;
    }
    __syncthreads();

    const float bb = b2p[0];
    const int tx = tid & 15;
    const int ty = tid >> 4;
    float* outb = out + (size_t)b * Nn * Nn;

    #pragma unroll
    for (int r = 0; r < 4; ++r) {
        const int i = ty * 4 + r;
        const float4 a = *(const float4*)(Sb + (size_t)(i0 + i) * Nn + j0 + tx * 4);
        float4 v;
        v.x = -0.5f * (fast_tanh(a.x + bb) + fast_tanh(bT[tx * 4 + 0][i] + bb));
        v.y = -0.5f * (fast_tanh(a.y + bb) + fast_tanh(bT[tx * 4 + 1][i] + bb));
        v.z = -0.5f * (fast_tanh(a.z + bb) + fast_tanh(bT[tx * 4 + 2][i] + bb));
        v.w = -0.5f * (fast_tanh(a.w + bb) + fast_tanh(bT[tx * 4 + 3][i] + bb));
        *(float4*)(outb + (size_t)(i0 + i) * Nn + j0 + tx * 4) = v;
    }
}

extern "C" void kernel_launch(void* const* d_in, const int* in_sizes, int n_in,
                              void* d_out, int out_size, void* d_ws, size_t ws_size,
                              hipStream_t stream) {
    const float* emb = (const float*)d_in[0];
    const float* W1  = (const float*)d_in[1];
    const float* b1  = (const float*)d_in[2];
    const float* W2  = (const float*)d_in[3];
    const float* b2  = (const float*)d_in[4];
    float* out = (float*)d_out;
    float* HI2 = (float*)d_ws;                        // 1 MB
    float* HJ  = HI2 + (size_t)Bb * Nn * Hh;          // 1 MB
    float* S   = HJ  + (size_t)Bb * Nn * Hh;          // 16.8 MB raw scores

    proj_kernel<<<(Bb * Nn) / 16, 512, 0, stream>>>(emb, W1, b1, HI2, HJ);
    score_kernel<<<Bb * 128, 256, 0, stream>>>(HI2, HJ, W2, S);
    sym_kernel<<<Bb * 256, 256, 0, stream>>>(S, b2, out);
}